// Round 15
// baseline (415.213 us; speedup 1.0000x reference)
//
#include <hip/hip_runtime.h>
#include <hip/hip_bf16.h>

typedef _Float16 half8_t __attribute__((ext_vector_type(8)));
typedef _Float16 half2_t __attribute__((ext_vector_type(2)));
typedef float float4_t __attribute__((ext_vector_type(4)));
typedef float float2_t __attribute__((ext_vector_type(2)));

// ---------------- radix-partition CSR build ----------------
// bucket b = dst >> SH (NBK <= 512). Edge chunks of CHUNK per workgroup.
// M[b*WG + w] = #edges of chunk w landing in bucket b; after k_colscan it is
// the per-chunk exclusive offset within bucket b. All hot counters are LDS
// (round-9 lesson: global scattered atomics cost ~10x the LDS-bucketed path).

__global__ __launch_bounds__(256) void k_hist(const int* __restrict__ dst, int E, int SH,
                                              int NBK, int WG, int CH, int* __restrict__ M) {
    extern __shared__ int lh[];
    for (int i = threadIdx.x; i < NBK; i += 256) lh[i] = 0;
    __syncthreads();
    int wg = blockIdx.x;
    int e0 = wg * CH, e1 = min(E, e0 + CH);
    for (int e = e0 + threadIdx.x; e < e1; e += 256)
        atomicAdd(&lh[dst[e] >> SH], 1);
    __syncthreads();
    for (int i = threadIdx.x; i < NBK; i += 256) M[i * WG + wg] = lh[i];
}

__global__ __launch_bounds__(256) void k_colscan(int* __restrict__ M, int WG,
                                                 int* __restrict__ totals) {
    __shared__ int s[256];
    int b = blockIdx.x, t = threadIdx.x;
    int v = (t < WG) ? M[b * WG + t] : 0;
    s[t] = v;
    __syncthreads();
    for (int off = 1; off < 256; off <<= 1) {
        int u = (t >= off) ? s[t - off] : 0;
        __syncthreads();
        s[t] += u;
        __syncthreads();
    }
    if (t < WG) M[b * WG + t] = s[t] - v;   // exclusive within bucket
    if (t == 255) totals[b] = s[255];
}

__global__ __launch_bounds__(512) void k_bucketscan(const int* __restrict__ totals, int NBK,
                                                    int E, int* __restrict__ base) {
    __shared__ int s[512];
    int t = threadIdx.x;
    int v = (t < NBK) ? totals[t] : 0;
    s[t] = v;
    __syncthreads();
    for (int off = 1; off < 512; off <<= 1) {
        int u = (t >= off) ? s[t - off] : 0;
        __syncthreads();
        s[t] += u;
        __syncthreads();
    }
    if (t < NBK) base[t] = s[t] - v;
    if (t == 0) base[NBK] = E;
}

// pack: low 23 bits = src node, high 9 bits = dst - (b<<SH). Valid for N < 2^23, SH <= 9.
__global__ __launch_bounds__(256) void k_scatter(const int* __restrict__ src,
                                                 const int* __restrict__ dst, int E, int SH,
                                                 int NBK, int WG, int CH,
                                                 const int* __restrict__ M,
                                                 const int* __restrict__ base,
                                                 unsigned* __restrict__ ebuf) {
    extern __shared__ int cur[];
    int wg = blockIdx.x;
    for (int i = threadIdx.x; i < NBK; i += 256) cur[i] = base[i] + M[i * WG + wg];
    __syncthreads();
    int e0 = wg * CH, e1 = min(E, e0 + CH);
    for (int e = e0 + threadIdx.x; e < e1; e += 256) {
        int d = dst[e];
        int b = d >> SH;
        int pos = atomicAdd(&cur[b], 1);                 // LDS atomic, wg-private
        ebuf[pos] = (unsigned)src[e] | ((unsigned)(d - (b << SH)) << 23);
    }
}

// one wg per bucket: LDS degree histogram -> local pair-scan -> rp/dinv, then
// second ebuf pass writes the STRIDED slot table (offset off -> idx
// (off&3)*8 + off>>2, quarter q owns offsets q, q+4, ...). Slots are NOT
// prefilled -- agg masks by off < deg. colx is written ONLY for overflow
// offsets >= 32 (remainder loop reads colx[k0+32..k1)).
// Idle-capacity side jobs: blocks 0..63 Wt transpose; 64 gptr search;
// 65..96 psum zero; 97 sums zero + fp8 zero-row of A8.
__global__ __launch_bounds__(256) void k_cntfill(const unsigned* __restrict__ ebuf,
                                                 const int* __restrict__ base, int SH, int N,
                                                 int E, float* __restrict__ dinv,
                                                 int* __restrict__ rp, int* __restrict__ colx,
                                                 int* __restrict__ slots,
                                                 const float* __restrict__ W0,
                                                 const float* __restrict__ W1,
                                                 _Float16* __restrict__ Wt0,
                                                 _Float16* __restrict__ Wt1,
                                                 const int* __restrict__ batch, int G,
                                                 int* __restrict__ gptr,
                                                 float* __restrict__ psum,
                                                 float* __restrict__ sums,
                                                 unsigned char* __restrict__ A8) {
    __shared__ int h[512];
    __shared__ int cur[512];
    __shared__ int rs[512];
    __shared__ int lim[512];
    __shared__ int s[256];
    int b = blockIdx.x, t = threadIdx.x;

    // side jobs
    if (b < 64) {
        int idx = b * 256 + t;            // 16384 elements over 64 blocks
        int n = idx >> 7, k = idx & 127;
        Wt0[n * 128 + k] = (_Float16)W0[k * 128 + n];
        Wt1[n * 128 + k] = (_Float16)W1[k * 128 + n];
    } else if (b == 64) {
        if (t <= G) {
            int g = t;
            int lo = 0, hi = N;
            while (lo < hi) {
                int mid = (lo + hi) >> 1;
                if (batch[mid] < g) lo = mid + 1; else hi = mid;
            }
            gptr[g] = lo;
        }
    } else if (b < 97) {
        int i0 = (b - 65) * 512 + t;      // G*128 = 16384 floats over 32 blocks
        psum[i0] = 0.f;
        psum[i0 + 256] = 0.f;
    } else if (b == 97) {
        if (t < 256) { sums[t] = 0.f; sums[t + 256] = 0.f; }
        // fp8 zero row at index N (mask target; e4m3 0.0 == 0x00)
        if (t < 32) ((unsigned*)A8)[(size_t)N * 32 + t] = 0u;
    }

    // main cntfill work
    int n0 = b << SH;
    int nb = min(N - n0, 1 << SH);
    for (int i = t; i < nb; i += 256) h[i] = 0;
    __syncthreads();
    int e0 = base[b], e1 = base[b + 1];
    for (int e = e0 + t; e < e1; e += 256)
        atomicAdd(&h[ebuf[e] >> 23], 1);
    __syncthreads();
    int i0 = 2 * t, i1 = 2 * t + 1;
    int a0 = (i0 < nb) ? h[i0] : 0;
    int a1 = (i1 < nb) ? h[i1] : 0;
    int ps = a0 + a1;
    s[t] = ps;
    __syncthreads();
    for (int off = 1; off < 256; off <<= 1) {
        int u = (t >= off) ? s[t - off] : 0;
        __syncthreads();
        s[t] += u;
        __syncthreads();
    }
    int excl = s[t] - ps;
    if (i0 < nb) {
        int r0 = e0 + excl;
        cur[i0] = r0;
        rs[i0] = r0;
        lim[i0] = min(a0, 32);
        rp[n0 + i0] = r0;
        dinv[n0 + i0] = rsqrtf((float)(a0 + 1));
    }
    if (i1 < nb) {
        int r1 = e0 + excl + a0;
        cur[i1] = r1;
        rs[i1] = r1;
        lim[i1] = min(a1, 32);
        rp[n0 + i1] = r1;
        dinv[n0 + i1] = rsqrtf((float)(a1 + 1));
    }
    if (b == (int)gridDim.x - 1 && t == 0) rp[N] = E;
    __syncthreads();
    for (int e = e0 + t; e < e1; e += 256) {
        unsigned v = ebuf[e];
        int local = (int)(v >> 23);
        int srcn = (int)(v & 0x7FFFFFu);
        int pos = atomicAdd(&cur[local], 1);             // LDS atomic, wg-private
        int off = pos - rs[local];
        if (slots && off < lim[local]) {
            int idx = ((off & 3) << 3) + (off >> 2);     // strided layout
            slots[(size_t)(n0 + local) * 32 + idx] = srcn;
        } else {
            colx[pos] = srcn;                            // overflow (or no-slots fallback)
        }
    }
}

// ---------------- MFMA GEMM layer 1 (N-split): out = fp8((X@W)*dinv) ----------------
// Round-11 counters: 1563 blocks, all pipes <11%, occ 33% -- wave-starved.
// Block = 16 rows; wave wv computes nt-tiles {2*wv, 2*wv+1} for the SAME
// rows -> 6250 blocks / 25000 waves (4x), X loads shared via L1, per-wave
// chain 2 B-loads + 2 MFMA per kc. (Resubmitted as a renamed artifact after
// three container-level failures of the identical source.)

__global__ __launch_bounds__(256) void k_gemmA(const float* __restrict__ X,
                                               const _Float16* __restrict__ Wt,
                                               const float* __restrict__ dinv,
                                               unsigned char* __restrict__ out, int N) {
    int t = threadIdx.x;
    int wv = t >> 6, lane = t & 63;
    int m = lane & 15, quad = lane >> 4;
    int rowbase = blockIdx.x * 16;
    int arow = rowbase + m;
    int arowc = (arow < N) ? arow : (N - 1);
    const float* xr = X + (size_t)arowc * 128;
    const _Float16* wt0 = Wt + (size_t)(wv * 2 * 16 + m) * 128;      // tile 2*wv
    const _Float16* wt1 = wt0 + (size_t)16 * 128;                    // tile 2*wv+1

    float4_t acc0 = (float4_t){0.f, 0.f, 0.f, 0.f};
    float4_t acc1 = (float4_t){0.f, 0.f, 0.f, 0.f};

    #pragma unroll
    for (int kc = 0; kc < 4; kc++) {
        int k0 = kc * 32 + quad * 8;
        float4_t xa = *(const float4_t*)(xr + k0);
        float4_t xb = *(const float4_t*)(xr + k0 + 4);
        half8_t a;
        a[0] = (_Float16)xa[0]; a[1] = (_Float16)xa[1];
        a[2] = (_Float16)xa[2]; a[3] = (_Float16)xa[3];
        a[4] = (_Float16)xb[0]; a[5] = (_Float16)xb[1];
        a[6] = (_Float16)xb[2]; a[7] = (_Float16)xb[3];
        half8_t b0 = *(const half8_t*)(wt0 + k0);
        half8_t b1 = *(const half8_t*)(wt1 + k0);
        acc0 = __builtin_amdgcn_mfma_f32_16x16x32_f16(a, b0, acc0, 0, 0, 0);
        acc1 = __builtin_amdgcn_mfma_f32_16x16x32_f16(a, b1, acc1, 0, 0, 0);
    }

    int ntb = wv * 2;
    #pragma unroll
    for (int r = 0; r < 4; r++) {
        int row = rowbase + quad * 4 + r;
        if (row < N) {
            float dv = dinv[row];
            unsigned char* o = out + (size_t)row * 128 + m;
            float v0 = acc0[r] * dv;
            float v1 = acc1[r] * dv;
            int p0 = __builtin_amdgcn_cvt_pk_fp8_f32(v0, v0, 0, false);
            int p1 = __builtin_amdgcn_cvt_pk_fp8_f32(v1, v1, 0, false);
            o[ntb * 16]       = (unsigned char)(p0 & 0xFF);
            o[(ntb + 1) * 16] = (unsigned char)(p1 & 0xFF);
        }
    }
}

// fp16-input variant, layer 2 (N-split): BN params computed per-block from
// sums, BN+ReLU fused into A-frag loads, fp8 output.
__global__ __launch_bounds__(256) void k_gemmB(const _Float16* __restrict__ X,
                                               const _Float16* __restrict__ Wt,
                                               const float* __restrict__ sums,
                                               const float* __restrict__ g,
                                               const float* __restrict__ be,
                                               const float* __restrict__ dinv,
                                               unsigned char* __restrict__ out, int N) {
    __shared__ alignas(16) float ss[128];
    __shared__ alignas(16) float hh[128];
    int t = threadIdx.x;
    if (t < 128) {
        float invN = 1.0f / (float)N;
        float mu = sums[t] * invN;
        float var = fmaxf(sums[128 + t] * invN - mu * mu, 0.f);
        float sc = g[t] * rsqrtf(var + 1e-5f);
        ss[t] = sc;
        hh[t] = fmaf(-mu, sc, be[t]);
    }
    __syncthreads();

    int wv = t >> 6, lane = t & 63;
    int m = lane & 15, quad = lane >> 4;
    int rowbase = blockIdx.x * 16;
    int arow = rowbase + m;
    int arowc = (arow < N) ? arow : (N - 1);
    const _Float16* xr = X + (size_t)arowc * 128;
    const _Float16* wt0 = Wt + (size_t)(wv * 2 * 16 + m) * 128;
    const _Float16* wt1 = wt0 + (size_t)16 * 128;

    float4_t acc0 = (float4_t){0.f, 0.f, 0.f, 0.f};
    float4_t acc1 = (float4_t){0.f, 0.f, 0.f, 0.f};

    #pragma unroll
    for (int kc = 0; kc < 4; kc++) {
        int k0 = kc * 32 + quad * 8;
        half8_t x8 = *(const half8_t*)(xr + k0);
        float4_t sa = *(const float4_t*)(ss + k0);
        float4_t sb = *(const float4_t*)(ss + k0 + 4);
        float4_t ha = *(const float4_t*)(hh + k0);
        float4_t hb = *(const float4_t*)(hh + k0 + 4);
        half8_t a;
        #pragma unroll
        for (int j = 0; j < 4; j++)
            a[j] = (_Float16)fmaxf(fmaf((float)x8[j], sa[j], ha[j]), 0.f);
        #pragma unroll
        for (int j = 0; j < 4; j++)
            a[4 + j] = (_Float16)fmaxf(fmaf((float)x8[4 + j], sb[j], hb[j]), 0.f);
        half8_t b0 = *(const half8_t*)(wt0 + k0);
        half8_t b1 = *(const half8_t*)(wt1 + k0);
        acc0 = __builtin_amdgcn_mfma_f32_16x16x32_f16(a, b0, acc0, 0, 0, 0);
        acc1 = __builtin_amdgcn_mfma_f32_16x16x32_f16(a, b1, acc1, 0, 0, 0);
    }

    int ntb = wv * 2;
    #pragma unroll
    for (int r = 0; r < 4; r++) {
        int row = rowbase + quad * 4 + r;
        if (row < N) {
            float dv = dinv[row];
            unsigned char* o = out + (size_t)row * 128 + m;
            float v0 = acc0[r] * dv;
            float v1 = acc1[r] * dv;
            int p0 = __builtin_amdgcn_cvt_pk_fp8_f32(v0, v0, 0, false);
            int p1 = __builtin_amdgcn_cvt_pk_fp8_f32(v1, v1, 0, false);
            o[ntb * 16]       = (unsigned char)(p0 & 0xFF);
            o[(ntb + 1) * 16] = (unsigned char)(p1 & 0xFF);
        }
    }
}

// ---------------- Aggregation: fp8 table + strided slots, degree-tiered ----------------
// out[i] = dinv[i]*(hs[i] + sum_j hs[j]) + b, fp16 out. One wave per node.
// Quarter q owns edge offsets q, q+4, ...; validity mask off < deg (slots
// unprefilled, garbage never dereferenced). deg>32 remainder reads
// colx[k0+32..k1) (written in cntfill for overflow offsets only).
// Decode: cvt_pk_f32_fp8 (2 vals/inst) into float2 accumulators.

__device__ __forceinline__ void acc8(uint2 v, float2_t* a2) {
    a2[0] += __builtin_amdgcn_cvt_pk_f32_fp8((int)v.x, false);
    a2[1] += __builtin_amdgcn_cvt_pk_f32_fp8((int)v.x, true);
    a2[2] += __builtin_amdgcn_cvt_pk_f32_fp8((int)v.y, false);
    a2[3] += __builtin_amdgcn_cvt_pk_f32_fp8((int)v.y, true);
}

__device__ __forceinline__ void f8x4(unsigned w, float* o) {
    o[0] = __builtin_amdgcn_cvt_f32_fp8((int)w, 0);
    o[1] = __builtin_amdgcn_cvt_f32_fp8((int)w, 1);
    o[2] = __builtin_amdgcn_cvt_f32_fp8((int)w, 2);
    o[3] = __builtin_amdgcn_cvt_f32_fp8((int)w, 3);
}

__global__ __launch_bounds__(256) void k_aggS8(const unsigned char* __restrict__ hs,
                                               const int* __restrict__ slots,
                                               const int* __restrict__ rp,
                                               const int* __restrict__ colx,
                                               const float* __restrict__ bias,
                                               _Float16* __restrict__ out, int N) {
    int wave = (blockIdx.x * 256 + threadIdx.x) >> 6;
    int lane = threadIdx.x & 63;
    if (wave >= N) return;
    int i = wave;
    int q = lane >> 4;            // quarter 0..3
    int c8 = lane & 15;           // channels 8*c8 .. 8*c8+7

    const int4* sl4 = (const int4*)(slots + (size_t)i * 32 + 8 * q);
    int4 sa = sl4[0];
    int k0 = rp[i], k1 = rp[i + 1];
    uint2 sw = *(const uint2*)(hs + (size_t)i * 128 + c8 * 8);   // self row
    int deg = k1 - k0;

    float2_t a2[4] = {{0.f, 0.f}, {0.f, 0.f}, {0.f, 0.f}, {0.f, 0.f}};

    // tier 1: edge offsets q, q+4, q+8, q+12 (covers deg<=16)
    {
        int jraw[4] = {sa.x, sa.y, sa.z, sa.w};
        int j[4];
        #pragma unroll
        for (int s = 0; s < 4; s++)
            j[s] = (q + 4 * s < deg) ? jraw[s] : N;   // mask unwritten slots
        uint2 v[4];
        #pragma unroll
        for (int s = 0; s < 4; s++)
            v[s] = *(const uint2*)(hs + (size_t)j[s] * 128 + c8 * 8);
        #pragma unroll
        for (int s = 0; s < 4; s++) acc8(v[s], a2);
    }
    if (deg > 16) {               // tier 2: offsets 16..31 (wave-uniform)
        int4 sb = sl4[1];
        int jraw[4] = {sb.x, sb.y, sb.z, sb.w};
        int j[4];
        #pragma unroll
        for (int s = 0; s < 4; s++)
            j[s] = (16 + q + 4 * s < deg) ? jraw[s] : N;
        uint2 v[4];
        #pragma unroll
        for (int s = 0; s < 4; s++)
            v[s] = *(const uint2*)(hs + (size_t)j[s] * 128 + c8 * 8);
        #pragma unroll
        for (int s = 0; s < 4; s++) acc8(v[s], a2);
        if (deg > 32) {           // rare remainder from colx (P ~ 1e-4)
            for (int k = k0 + 32 + q; k < k1; k += 4) {
                uint2 vv = *(const uint2*)(hs + (size_t)colx[k] * 128 + c8 * 8);
                acc8(vv, a2);
            }
        }
    }

    // cross-quarter reduce over lanes {l, l+16, l+32, l+48}
    float a[8] = {a2[0].x, a2[0].y, a2[1].x, a2[1].y,
                  a2[2].x, a2[2].y, a2[3].x, a2[3].y};
    #pragma unroll
    for (int t = 0; t < 8; t++) {
        float x = a[t];
        x += __shfl_xor(x, 16);
        x += __shfl_xor(x, 32);
        a[t] = x;
    }

    if (q == 0) {
        float d = rsqrtf((float)(deg + 1));
        float4 bA = ((const float4*)bias)[2 * c8];
        float4 bB = ((const float4*)bias)[2 * c8 + 1];
        float bb[8] = {bA.x, bA.y, bA.z, bA.w, bB.x, bB.y, bB.z, bB.w};
        float sf[8];
        f8x4(sw.x, sf);
        f8x4(sw.y, sf + 4);
        half8_t o;
        #pragma unroll
        for (int t = 0; t < 8; t++)
            o[t] = (_Float16)fmaf(a[t] + sf[t], d, bb[t]);
        ((half8_t*)out)[(size_t)i * 16 + c8] = o;
    }
}

// CSR fallback (fp8) if workspace can't hold the slot table (colx holds all).
__global__ __launch_bounds__(256) void k_aggC8(const unsigned char* __restrict__ hs,
                                               const int* __restrict__ rp,
                                               const int* __restrict__ colx,
                                               const float* __restrict__ bias,
                                               _Float16* __restrict__ out, int N) {
    int wave = (blockIdx.x * 256 + threadIdx.x) >> 6;
    int lane = threadIdx.x & 63;
    if (wave >= N) return;
    int i = wave;
    int q = lane >> 4;
    int c8 = lane & 15;

    uint2 sw = *(const uint2*)(hs + (size_t)i * 128 + c8 * 8);
    int k0 = rp[i], k1 = rp[i + 1];

    float2_t a2[4] = {{0.f, 0.f}, {0.f, 0.f}, {0.f, 0.f}, {0.f, 0.f}};
    for (int k = k0 + q; k < k1; k += 4) {
        uint2 vv = *(const uint2*)(hs + (size_t)colx[k] * 128 + c8 * 8);
        acc8(vv, a2);
    }

    float a[8] = {a2[0].x, a2[0].y, a2[1].x, a2[1].y,
                  a2[2].x, a2[2].y, a2[3].x, a2[3].y};
    #pragma unroll
    for (int t = 0; t < 8; t++) {
        float x = a[t];
        x += __shfl_xor(x, 16);
        x += __shfl_xor(x, 32);
        a[t] = x;
    }

    if (q == 0) {
        float d = rsqrtf((float)(k1 - k0 + 1));
        float4 bA = ((const float4*)bias)[2 * c8];
        float4 bB = ((const float4*)bias)[2 * c8 + 1];
        float bb[8] = {bA.x, bA.y, bA.z, bA.w, bB.x, bB.y, bB.z, bB.w};
        float sf[8];
        f8x4(sw.x, sf);
        f8x4(sw.y, sf + 4);
        half8_t o;
        #pragma unroll
        for (int t = 0; t < 8; t++)
            o[t] = (_Float16)fmaf(a[t] + sf[t], d, bb[t]);
        ((half8_t*)out)[(size_t)i * 16 + c8] = o;
    }
}

// ---------------- BN stats (fp16 input) ----------------

__global__ __launch_bounds__(256) void k_stats(const _Float16* __restrict__ x, int N,
                                               float* __restrict__ sums) {
    int lane = threadIdx.x & 63;
    int wv = threadIdx.x >> 6;
    int gw = blockIdx.x * 4 + wv;
    int stride = gridDim.x * 4;
    const half2_t* b = (const half2_t*)x;
    float2 s = make_float2(0.f, 0.f), q = make_float2(0.f, 0.f);
    for (int i = gw; i < N; i += stride) {
        half2_t v = b[(size_t)i * 64 + lane];
        float vx = (float)v.x, vy = (float)v.y;
        s.x += vx; s.y += vy;
        q.x += vx * vx; q.y += vy * vy;
    }
    __shared__ float ls[4][128];
    __shared__ float lq[4][128];
    ls[wv][2 * lane] = s.x; ls[wv][2 * lane + 1] = s.y;
    lq[wv][2 * lane] = q.x; lq[wv][2 * lane + 1] = q.y;
    __syncthreads();
    int t = threadIdx.x;
    if (t < 128) {
        float ts = ls[0][t] + ls[1][t] + ls[2][t] + ls[3][t];
        float tq = lq[0][t] + lq[1][t] + lq[2][t] + lq[3][t];
        atomicAdd(&sums[t], ts);
        atomicAdd(&sums[128 + t], tq);
    }
}

// ---------------- Pooling: node-parallel, per-wave run flush (fp16 input) ----------------
// BN2 params computed per-block from sums.

__global__ __launch_bounds__(256) void k_pool2(const _Float16* __restrict__ x,
                                               const int* __restrict__ batch,
                                               const float* __restrict__ sums,
                                               const float* __restrict__ g2,
                                               const float* __restrict__ be2,
                                               float* __restrict__ psum, int N) {
    __shared__ alignas(8) float ss[128];
    __shared__ alignas(8) float hh[128];
    int t = threadIdx.x;
    if (t < 128) {
        float invN = 1.0f / (float)N;
        float mu = sums[t] * invN;
        float var = fmaxf(sums[128 + t] * invN - mu * mu, 0.f);
        float sc = g2[t] * rsqrtf(var + 1e-5f);
        ss[t] = sc;
        hh[t] = fmaf(-mu, sc, be2[t]);
    }
    __syncthreads();

    int nw = gridDim.x * 4;
    int w = blockIdx.x * 4 + (threadIdx.x >> 6);
    int lane = threadIdx.x & 63;
    int per = (N + nw - 1) / nw;
    int i0 = w * per, i1 = min(N, i0 + per);
    if (i0 >= i1) return;
    const half2_t* b = (const half2_t*)x;
    float2 s2 = ((const float2*)ss)[lane];
    float2 h2 = ((const float2*)hh)[lane];
    float2 acc = make_float2(0.f, 0.f);
    int g = batch[i0];
    for (int i = i0; i < i1; i++) {
        int gi = batch[i];
        if (gi != g) {   // wave-uniform branch
            atomicAdd(&psum[g * 128 + 2 * lane], acc.x);
            atomicAdd(&psum[g * 128 + 2 * lane + 1], acc.y);
            acc = make_float2(0.f, 0.f);
            g = gi;
        }
        half2_t v = b[(size_t)i * 64 + lane];
        acc.x += fmaxf(fmaf((float)v.x, s2.x, h2.x), 0.f);
        acc.y += fmaxf(fmaf((float)v.y, s2.y, h2.y), 0.f);
    }
    atomicAdd(&psum[g * 128 + 2 * lane], acc.x);
    atomicAdd(&psum[g * 128 + 2 * lane + 1], acc.y);
}

// ---------------- Head: out[g][o] = (psum[g]/cnt[g]) @ Wout[:,o] + bout[o] ----------------

__global__ __launch_bounds__(64) void k_final(const float* __restrict__ psum,
                                              const int* __restrict__ gptr,
                                              const float* __restrict__ Wout,
                                              const float* __restrict__ bout,
                                              float* __restrict__ out, int O) {
    int g = blockIdx.x, o = threadIdx.x;
    int cnt = gptr[g + 1] - gptr[g];
    float inv = 1.0f / fmaxf((float)cnt, 1.f);
    float acc = 0.f;
    for (int c = 0; c < 128; c++) acc = fmaf(psum[g * 128 + c], Wout[c * O + o], acc);
    out[g * O + o] = fmaf(acc, inv, bout[o]);
}

// ---------------- Host launch ----------------

extern "C" void kernel_launch(void* const* d_in, const int* in_sizes, int n_in,
                              void* d_out, int out_size, void* d_ws, size_t ws_size,
                              hipStream_t stream) {
    const float* x    = (const float*)d_in[0];
    const int*   edge = (const int*)d_in[1];
    const int*   batch= (const int*)d_in[2];
    const float* W0   = (const float*)d_in[4];
    const float* b0   = (const float*)d_in[5];
    const float* g0   = (const float*)d_in[6];
    const float* be0  = (const float*)d_in[7];
    const float* W1   = (const float*)d_in[8];
    const float* b1   = (const float*)d_in[9];
    const float* g1   = (const float*)d_in[10];
    const float* be1  = (const float*)d_in[11];
    const float* Wout = (const float*)d_in[12];
    const float* bout = (const float*)d_in[13];
    float* out = (float*)d_out;

    const int Hh  = in_sizes[5];              // 128
    const int Fin = in_sizes[4] / Hh;         // 128
    const int N   = in_sizes[0] / Fin;        // 100000
    const int E   = in_sizes[1] / 2;          // 1600000
    const int O   = in_sizes[13];             // 64
    const int G   = out_size / O;             // 128
    (void)Hh; (void)n_in;

    // bucket shift: smallest SH >= 8 with <= 512 buckets (pack needs SH <= 9, N < 2^23)
    int SH = 8;
    while (((N + (1 << SH) - 1) >> SH) > 512) SH++;
    const int NBK = (N + (1 << SH) - 1) >> SH;
    const int CH  = ((E + 255) / 256 > 8192) ? (E + 255) / 256 : 8192;  // chunk, keep WG<=256
    const int WG  = (E + CH - 1) / CH;

    char* p = (char*)d_ws;
    auto alloc = [&](size_t bytes) -> void* {
        void* r = (void*)p;
        p += (bytes + 255) & ~(size_t)255;
        return r;
    };
    unsigned char* A8 = (unsigned char*)alloc((size_t)(N + 1) * 128); // fp8 gather table + zero row
    _Float16* B   = (_Float16*)alloc((size_t)N * 128 * 2);            // fp16 layer output
    float* dinv   = (float*)alloc((size_t)N * 4);
    int*   rp     = (int*)alloc((size_t)(N + 1) * 4);
    int*   colx   = (int*)alloc((size_t)E * 4);
    unsigned* ebuf= (unsigned*)alloc((size_t)E * 4);
    int*   M      = (int*)alloc((size_t)NBK * WG * 4);
    int*   totals = (int*)alloc((size_t)NBK * 4);
    int*   base   = (int*)alloc((size_t)(NBK + 1) * 4);
    float* sums   = (float*)alloc(512 * 4);   // [sum1|sq1|sum2|sq2]
    int*   gptr   = (int*)alloc((size_t)(G + 1) * 4);
    float* psum   = (float*)alloc((size_t)G * 128 * 4);
    _Float16* Wt0 = (_Float16*)alloc(128 * 128 * 2);
    _Float16* Wt1 = (_Float16*)alloc(128 * 128 * 2);
    int*   slots  = (int*)alloc((size_t)N * 32 * 4);   // fixed-width gather slots
    bool useSlots = ((size_t)(p - (char*)d_ws) <= ws_size);
    if (!useSlots) slots = nullptr;

    const int* src = edge;
    const int* dst = edge + E;

    // radix-partition CSR build (LDS atomics); cntfill also does side jobs
    k_hist<<<WG, 256, NBK * 4, stream>>>(dst, E, SH, NBK, WG, CH, M);
    k_colscan<<<NBK, 256, 0, stream>>>(M, WG, totals);
    k_bucketscan<<<1, 512, 0, stream>>>(totals, NBK, E, base);
    k_scatter<<<WG, 256, NBK * 4, stream>>>(src, dst, E, SH, NBK, WG, CH, M, base, ebuf);
    k_cntfill<<<NBK, 256, 0, stream>>>(ebuf, base, SH, N, E, dinv, rp, colx, slots,
                                       W0, W1, Wt0, Wt1, batch, G, gptr, psum, sums, A8);

    // Layer 1 (MFMA GEMM fp32 in, fp8 out -> fp8 gather)
    k_gemmA<<<(N + 15) / 16, 256, 0, stream>>>(x, Wt0, dinv, A8, N);
    if (useSlots)
        k_aggS8<<<(N + 3) / 4, 256, 0, stream>>>(A8, slots, rp, colx, b0, B, N);
    else
        k_aggC8<<<(N + 3) / 4, 256, 0, stream>>>(A8, rp, colx, b0, B, N);
    k_stats<<<512, 256, 0, stream>>>(B, N, sums);

    // Layer 2 (fp16 in, BN1 params computed in-kernel, fp8 out -> fp8 gather)
    k_gemmB<<<(N + 15) / 16, 256, 0, stream>>>(B, Wt1, sums, g0, be0, dinv, A8, N);
    if (useSlots)
        k_aggS8<<<(N + 3) / 4, 256, 0, stream>>>(A8, slots, rp, colx, b1, B, N);
    else
        k_aggC8<<<(N + 3) / 4, 256, 0, stream>>>(A8, rp, colx, b1, B, N);
    k_stats<<<512, 256, 0, stream>>>(B, N, sums + 256);

    // Pool (BN2 computed in-kernel, BN+ReLU fused) + head (mean division fused)
    k_pool2<<<512, 256, 0, stream>>>(B, batch, sums + 256, g1, be1, psum, N);
    k_final<<<G, 64, 0, stream>>>(psum, gptr, Wout, bout, out, O);
}

// Round 16
// 354.975 us; speedup vs baseline: 1.1697x; 1.1697x over previous
//
#include <hip/hip_runtime.h>
#include <hip/hip_bf16.h>

typedef _Float16 half8_t __attribute__((ext_vector_type(8)));
typedef _Float16 half2_t __attribute__((ext_vector_type(2)));
typedef float float4_t __attribute__((ext_vector_type(4)));
typedef float float2_t __attribute__((ext_vector_type(2)));

#define WROW 136   // LDS Wt row pitch in halfs: 272B, 16B-aligned, bank-optimal

// ---------------- radix-partition CSR build ----------------
// bucket b = dst >> SH (NBK <= 512). Edge chunks of CHUNK per workgroup.
// M[b*WG + w] = #edges of chunk w landing in bucket b; after k_colscan it is
// the per-chunk exclusive offset within bucket b. All hot counters are LDS
// (round-9 lesson: global scattered atomics cost ~10x the LDS-bucketed path).

__global__ __launch_bounds__(256) void k_hist(const int* __restrict__ dst, int E, int SH,
                                              int NBK, int WG, int CH, int* __restrict__ M) {
    extern __shared__ int lh[];
    for (int i = threadIdx.x; i < NBK; i += 256) lh[i] = 0;
    __syncthreads();
    int wg = blockIdx.x;
    int e0 = wg * CH, e1 = min(E, e0 + CH);
    for (int e = e0 + threadIdx.x; e < e1; e += 256)
        atomicAdd(&lh[dst[e] >> SH], 1);
    __syncthreads();
    for (int i = threadIdx.x; i < NBK; i += 256) M[i * WG + wg] = lh[i];
}

__global__ __launch_bounds__(256) void k_colscan(int* __restrict__ M, int WG,
                                                 int* __restrict__ totals) {
    __shared__ int s[256];
    int b = blockIdx.x, t = threadIdx.x;
    int v = (t < WG) ? M[b * WG + t] : 0;
    s[t] = v;
    __syncthreads();
    for (int off = 1; off < 256; off <<= 1) {
        int u = (t >= off) ? s[t - off] : 0;
        __syncthreads();
        s[t] += u;
        __syncthreads();
    }
    if (t < WG) M[b * WG + t] = s[t] - v;   // exclusive within bucket
    if (t == 255) totals[b] = s[255];
}

__global__ __launch_bounds__(512) void k_bucketscan(const int* __restrict__ totals, int NBK,
                                                    int E, int* __restrict__ base) {
    __shared__ int s[512];
    int t = threadIdx.x;
    int v = (t < NBK) ? totals[t] : 0;
    s[t] = v;
    __syncthreads();
    for (int off = 1; off < 512; off <<= 1) {
        int u = (t >= off) ? s[t - off] : 0;
        __syncthreads();
        s[t] += u;
        __syncthreads();
    }
    if (t < NBK) base[t] = s[t] - v;
    if (t == 0) base[NBK] = E;
}

// pack: low 23 bits = src node, high 9 bits = dst - (b<<SH). Valid for N < 2^23, SH <= 9.
__global__ __launch_bounds__(256) void k_scatter(const int* __restrict__ src,
                                                 const int* __restrict__ dst, int E, int SH,
                                                 int NBK, int WG, int CH,
                                                 const int* __restrict__ M,
                                                 const int* __restrict__ base,
                                                 unsigned* __restrict__ ebuf) {
    extern __shared__ int cur[];
    int wg = blockIdx.x;
    for (int i = threadIdx.x; i < NBK; i += 256) cur[i] = base[i] + M[i * WG + wg];
    __syncthreads();
    int e0 = wg * CH, e1 = min(E, e0 + CH);
    for (int e = e0 + threadIdx.x; e < e1; e += 256) {
        int d = dst[e];
        int b = d >> SH;
        int pos = atomicAdd(&cur[b], 1);                 // LDS atomic, wg-private
        ebuf[pos] = (unsigned)src[e] | ((unsigned)(d - (b << SH)) << 23);
    }
}

// one wg per bucket: LDS degree histogram -> local pair-scan -> rp/dinv, then
// second ebuf pass writes the STRIDED slot table (offset off -> idx
// (off&3)*8 + off>>2, quarter q owns offsets q, q+4, ...). Slots are NOT
// prefilled -- agg masks by off < deg. colx is written ONLY for overflow
// offsets >= 32 (remainder loop reads colx[k0+32..k1)).
// Idle-capacity side jobs: blocks 0..63 Wt transpose; 64 gptr search;
// 65..96 psum zero; 97 sums zero + fp8 zero-row of A8.
__global__ __launch_bounds__(256) void k_cntfill(const unsigned* __restrict__ ebuf,
                                                 const int* __restrict__ base, int SH, int N,
                                                 int E, float* __restrict__ dinv,
                                                 int* __restrict__ rp, int* __restrict__ colx,
                                                 int* __restrict__ slots,
                                                 const float* __restrict__ W0,
                                                 const float* __restrict__ W1,
                                                 _Float16* __restrict__ Wt0,
                                                 _Float16* __restrict__ Wt1,
                                                 const int* __restrict__ batch, int G,
                                                 int* __restrict__ gptr,
                                                 float* __restrict__ psum,
                                                 float* __restrict__ sums,
                                                 unsigned char* __restrict__ A8) {
    __shared__ int h[512];
    __shared__ int cur[512];
    __shared__ int rs[512];
    __shared__ int lim[512];
    __shared__ int s[256];
    int b = blockIdx.x, t = threadIdx.x;

    // side jobs
    if (b < 64) {
        int idx = b * 256 + t;            // 16384 elements over 64 blocks
        int n = idx >> 7, k = idx & 127;
        Wt0[n * 128 + k] = (_Float16)W0[k * 128 + n];
        Wt1[n * 128 + k] = (_Float16)W1[k * 128 + n];
    } else if (b == 64) {
        if (t <= G) {
            int g = t;
            int lo = 0, hi = N;
            while (lo < hi) {
                int mid = (lo + hi) >> 1;
                if (batch[mid] < g) lo = mid + 1; else hi = mid;
            }
            gptr[g] = lo;
        }
    } else if (b < 97) {
        int i0 = (b - 65) * 512 + t;      // G*128 = 16384 floats over 32 blocks
        psum[i0] = 0.f;
        psum[i0 + 256] = 0.f;
    } else if (b == 97) {
        if (t < 256) { sums[t] = 0.f; sums[t + 256] = 0.f; }
        // fp8 zero row at index N (mask target; e4m3 0.0 == 0x00)
        if (t < 32) ((unsigned*)A8)[(size_t)N * 32 + t] = 0u;
    }

    // main cntfill work
    int n0 = b << SH;
    int nb = min(N - n0, 1 << SH);
    for (int i = t; i < nb; i += 256) h[i] = 0;
    __syncthreads();
    int e0 = base[b], e1 = base[b + 1];
    for (int e = e0 + t; e < e1; e += 256)
        atomicAdd(&h[ebuf[e] >> 23], 1);
    __syncthreads();
    int i0 = 2 * t, i1 = 2 * t + 1;
    int a0 = (i0 < nb) ? h[i0] : 0;
    int a1 = (i1 < nb) ? h[i1] : 0;
    int ps = a0 + a1;
    s[t] = ps;
    __syncthreads();
    for (int off = 1; off < 256; off <<= 1) {
        int u = (t >= off) ? s[t - off] : 0;
        __syncthreads();
        s[t] += u;
        __syncthreads();
    }
    int excl = s[t] - ps;
    if (i0 < nb) {
        int r0 = e0 + excl;
        cur[i0] = r0;
        rs[i0] = r0;
        lim[i0] = min(a0, 32);
        rp[n0 + i0] = r0;
        dinv[n0 + i0] = rsqrtf((float)(a0 + 1));
    }
    if (i1 < nb) {
        int r1 = e0 + excl + a0;
        cur[i1] = r1;
        rs[i1] = r1;
        lim[i1] = min(a1, 32);
        rp[n0 + i1] = r1;
        dinv[n0 + i1] = rsqrtf((float)(a1 + 1));
    }
    if (b == (int)gridDim.x - 1 && t == 0) rp[N] = E;
    __syncthreads();
    for (int e = e0 + t; e < e1; e += 256) {
        unsigned v = ebuf[e];
        int local = (int)(v >> 23);
        int srcn = (int)(v & 0x7FFFFFu);
        int pos = atomicAdd(&cur[local], 1);             // LDS atomic, wg-private
        int off = pos - rs[local];
        if (slots && off < lim[local]) {
            int idx = ((off & 3) << 3) + (off >> 2);     // strided layout
            slots[(size_t)(n0 + local) * 32 + idx] = srcn;
        } else {
            colx[pos] = srcn;                            // overflow (or no-slots fallback)
        }
    }
}

// ---------------- MFMA GEMM layer 1: out = fp8((X@W)*dinv) ----------------
// Round-15 post-mortem: VGPR_Count=20 -> compiler serialized every global
// load (each wave = ~16 sequential L2/L3 round trips; occupancy couldn't
// cover it; N-split made it worse). Fix: stage Wt in LDS once per block
// (coalesced), batch-issue ALL X loads up front, inner loop is ds_read+MFMA
// only. Wt row pitch 136 halfs (272B): 16B-aligned, bank-optimal for the
// 16-row x 4-quad ds_read_b128 pattern. 64-row blocks, 4 waves x 8 tiles.

__global__ __launch_bounds__(256) void k_gemmA(const float* __restrict__ X,
                                               const _Float16* __restrict__ Wt,
                                               const float* __restrict__ dinv,
                                               unsigned char* __restrict__ out, int N) {
    __shared__ _Float16 w[128 * WROW];
    int t = threadIdx.x;
    #pragma unroll
    for (int i = 0; i < 8; i++) {
        int idx = t + i * 256;            // 2048 chunks of 8 halfs
        int n = idx >> 4, k = (idx & 15) * 8;
        *(half8_t*)&w[n * WROW + k] = *(const half8_t*)(Wt + n * 128 + k);
    }
    __syncthreads();

    int wv = t >> 6, lane = t & 63;
    int m = lane & 15, quad = lane >> 4;
    int rowbase = blockIdx.x * 64 + wv * 16;
    int arow = rowbase + m;
    int arowc = (arow < N) ? arow : (N - 1);
    const float* xr = X + (size_t)arowc * 128;

    // batch-issue all X loads (one memory epoch per wave)
    float4_t xa[4], xb[4];
    #pragma unroll
    for (int kc = 0; kc < 4; kc++) {
        xa[kc] = *(const float4_t*)(xr + kc * 32 + quad * 8);
        xb[kc] = *(const float4_t*)(xr + kc * 32 + quad * 8 + 4);
    }
    half8_t a[4];
    #pragma unroll
    for (int kc = 0; kc < 4; kc++) {
        #pragma unroll
        for (int j = 0; j < 4; j++) a[kc][j] = (_Float16)xa[kc][j];
        #pragma unroll
        for (int j = 0; j < 4; j++) a[kc][4 + j] = (_Float16)xb[kc][j];
    }

    float4_t acc[8];
    #pragma unroll
    for (int i = 0; i < 8; i++) acc[i] = (float4_t){0.f, 0.f, 0.f, 0.f};

    #pragma unroll
    for (int nt = 0; nt < 8; nt++) {
        const _Float16* wr = &w[(nt * 16 + m) * WROW + quad * 8];
        #pragma unroll
        for (int kc = 0; kc < 4; kc++) {
            half8_t b = *(const half8_t*)(wr + kc * 32);
            acc[nt] = __builtin_amdgcn_mfma_f32_16x16x32_f16(a[kc], b, acc[nt], 0, 0, 0);
        }
    }

    #pragma unroll
    for (int r = 0; r < 4; r++) {
        int row = rowbase + quad * 4 + r;
        if (row < N) {
            float dv = dinv[row];
            unsigned char* o = out + (size_t)row * 128 + m;
            #pragma unroll
            for (int nt = 0; nt < 8; nt++) {
                float v = acc[nt][r] * dv;
                int pk = __builtin_amdgcn_cvt_pk_fp8_f32(v, v, 0, false);
                o[nt * 16] = (unsigned char)(pk & 0xFF);
            }
        }
    }
}

// fp16-input variant, layer 2: Wt in LDS, BN params computed per-block from
// sums, BN+ReLU fused into A-frag conversion, fp8 output.
__global__ __launch_bounds__(256) void k_gemmB(const _Float16* __restrict__ X,
                                               const _Float16* __restrict__ Wt,
                                               const float* __restrict__ sums,
                                               const float* __restrict__ g,
                                               const float* __restrict__ be,
                                               const float* __restrict__ dinv,
                                               unsigned char* __restrict__ out, int N) {
    __shared__ _Float16 w[128 * WROW];
    __shared__ alignas(16) float ss[128];
    __shared__ alignas(16) float hh[128];
    int t = threadIdx.x;
    if (t < 128) {
        float invN = 1.0f / (float)N;
        float mu = sums[t] * invN;
        float var = fmaxf(sums[128 + t] * invN - mu * mu, 0.f);
        float sc = g[t] * rsqrtf(var + 1e-5f);
        ss[t] = sc;
        hh[t] = fmaf(-mu, sc, be[t]);
    }
    #pragma unroll
    for (int i = 0; i < 8; i++) {
        int idx = t + i * 256;
        int n = idx >> 4, k = (idx & 15) * 8;
        *(half8_t*)&w[n * WROW + k] = *(const half8_t*)(Wt + n * 128 + k);
    }
    __syncthreads();

    int wv = t >> 6, lane = t & 63;
    int m = lane & 15, quad = lane >> 4;
    int rowbase = blockIdx.x * 64 + wv * 16;
    int arow = rowbase + m;
    int arowc = (arow < N) ? arow : (N - 1);
    const _Float16* xr = X + (size_t)arowc * 128;

    // batch-issue all X loads
    half8_t x8[4];
    #pragma unroll
    for (int kc = 0; kc < 4; kc++)
        x8[kc] = *(const half8_t*)(xr + kc * 32 + quad * 8);

    half8_t a[4];
    #pragma unroll
    for (int kc = 0; kc < 4; kc++) {
        int k0 = kc * 32 + quad * 8;
        float4_t sa = *(const float4_t*)(ss + k0);
        float4_t sb = *(const float4_t*)(ss + k0 + 4);
        float4_t ha = *(const float4_t*)(hh + k0);
        float4_t hb = *(const float4_t*)(hh + k0 + 4);
        #pragma unroll
        for (int j = 0; j < 4; j++)
            a[kc][j] = (_Float16)fmaxf(fmaf((float)x8[kc][j], sa[j], ha[j]), 0.f);
        #pragma unroll
        for (int j = 0; j < 4; j++)
            a[kc][4 + j] = (_Float16)fmaxf(fmaf((float)x8[kc][4 + j], sb[j], hb[j]), 0.f);
    }

    float4_t acc[8];
    #pragma unroll
    for (int i = 0; i < 8; i++) acc[i] = (float4_t){0.f, 0.f, 0.f, 0.f};

    #pragma unroll
    for (int nt = 0; nt < 8; nt++) {
        const _Float16* wr = &w[(nt * 16 + m) * WROW + quad * 8];
        #pragma unroll
        for (int kc = 0; kc < 4; kc++) {
            half8_t b = *(const half8_t*)(wr + kc * 32);
            acc[nt] = __builtin_amdgcn_mfma_f32_16x16x32_f16(a[kc], b, acc[nt], 0, 0, 0);
        }
    }

    #pragma unroll
    for (int r = 0; r < 4; r++) {
        int row = rowbase + quad * 4 + r;
        if (row < N) {
            float dv = dinv[row];
            unsigned char* o = out + (size_t)row * 128 + m;
            #pragma unroll
            for (int nt = 0; nt < 8; nt++) {
                float v = acc[nt][r] * dv;
                int pk = __builtin_amdgcn_cvt_pk_fp8_f32(v, v, 0, false);
                o[nt * 16] = (unsigned char)(pk & 0xFF);
            }
        }
    }
}

// ---------------- Aggregation: fp8 table + strided slots, degree-tiered ----------------
// out[i] = dinv[i]*(hs[i] + sum_j hs[j]) + b, fp16 out. One wave per node.
// Quarter q owns edge offsets q, q+4, ...; validity mask off < deg (slots
// unprefilled, garbage never dereferenced). deg>32 remainder reads
// colx[k0+32..k1) (written in cntfill for overflow offsets only).
// Decode: cvt_pk_f32_fp8 (2 vals/inst) into float2 accumulators.

__device__ __forceinline__ void acc8(uint2 v, float2_t* a2) {
    a2[0] += __builtin_amdgcn_cvt_pk_f32_fp8((int)v.x, false);
    a2[1] += __builtin_amdgcn_cvt_pk_f32_fp8((int)v.x, true);
    a2[2] += __builtin_amdgcn_cvt_pk_f32_fp8((int)v.y, false);
    a2[3] += __builtin_amdgcn_cvt_pk_f32_fp8((int)v.y, true);
}

__device__ __forceinline__ void f8x4(unsigned w, float* o) {
    o[0] = __builtin_amdgcn_cvt_f32_fp8((int)w, 0);
    o[1] = __builtin_amdgcn_cvt_f32_fp8((int)w, 1);
    o[2] = __builtin_amdgcn_cvt_f32_fp8((int)w, 2);
    o[3] = __builtin_amdgcn_cvt_f32_fp8((int)w, 3);
}

__global__ __launch_bounds__(256) void k_aggS8(const unsigned char* __restrict__ hs,
                                               const int* __restrict__ slots,
                                               const int* __restrict__ rp,
                                               const int* __restrict__ colx,
                                               const float* __restrict__ bias,
                                               _Float16* __restrict__ out, int N) {
    int wave = (blockIdx.x * 256 + threadIdx.x) >> 6;
    int lane = threadIdx.x & 63;
    if (wave >= N) return;
    int i = wave;
    int q = lane >> 4;            // quarter 0..3
    int c8 = lane & 15;           // channels 8*c8 .. 8*c8+7

    const int4* sl4 = (const int4*)(slots + (size_t)i * 32 + 8 * q);
    int4 sa = sl4[0];
    int k0 = rp[i], k1 = rp[i + 1];
    uint2 sw = *(const uint2*)(hs + (size_t)i * 128 + c8 * 8);   // self row
    int deg = k1 - k0;

    float2_t a2[4] = {{0.f, 0.f}, {0.f, 0.f}, {0.f, 0.f}, {0.f, 0.f}};

    // tier 1: edge offsets q, q+4, q+8, q+12 (covers deg<=16)
    {
        int jraw[4] = {sa.x, sa.y, sa.z, sa.w};
        int j[4];
        #pragma unroll
        for (int s = 0; s < 4; s++)
            j[s] = (q + 4 * s < deg) ? jraw[s] : N;   // mask unwritten slots
        uint2 v[4];
        #pragma unroll
        for (int s = 0; s < 4; s++)
            v[s] = *(const uint2*)(hs + (size_t)j[s] * 128 + c8 * 8);
        #pragma unroll
        for (int s = 0; s < 4; s++) acc8(v[s], a2);
    }
    if (deg > 16) {               // tier 2: offsets 16..31 (wave-uniform)
        int4 sb = sl4[1];
        int jraw[4] = {sb.x, sb.y, sb.z, sb.w};
        int j[4];
        #pragma unroll
        for (int s = 0; s < 4; s++)
            j[s] = (16 + q + 4 * s < deg) ? jraw[s] : N;
        uint2 v[4];
        #pragma unroll
        for (int s = 0; s < 4; s++)
            v[s] = *(const uint2*)(hs + (size_t)j[s] * 128 + c8 * 8);
        #pragma unroll
        for (int s = 0; s < 4; s++) acc8(v[s], a2);
        if (deg > 32) {           // rare remainder from colx (P ~ 1e-4)
            for (int k = k0 + 32 + q; k < k1; k += 4) {
                uint2 vv = *(const uint2*)(hs + (size_t)colx[k] * 128 + c8 * 8);
                acc8(vv, a2);
            }
        }
    }

    // cross-quarter reduce over lanes {l, l+16, l+32, l+48}
    float a[8] = {a2[0].x, a2[0].y, a2[1].x, a2[1].y,
                  a2[2].x, a2[2].y, a2[3].x, a2[3].y};
    #pragma unroll
    for (int t = 0; t < 8; t++) {
        float x = a[t];
        x += __shfl_xor(x, 16);
        x += __shfl_xor(x, 32);
        a[t] = x;
    }

    if (q == 0) {
        float d = rsqrtf((float)(deg + 1));
        float4 bA = ((const float4*)bias)[2 * c8];
        float4 bB = ((const float4*)bias)[2 * c8 + 1];
        float bb[8] = {bA.x, bA.y, bA.z, bA.w, bB.x, bB.y, bB.z, bB.w};
        float sf[8];
        f8x4(sw.x, sf);
        f8x4(sw.y, sf + 4);
        half8_t o;
        #pragma unroll
        for (int t = 0; t < 8; t++)
            o[t] = (_Float16)fmaf(a[t] + sf[t], d, bb[t]);
        ((half8_t*)out)[(size_t)i * 16 + c8] = o;
    }
}

// CSR fallback (fp8) if workspace can't hold the slot table (colx holds all).
__global__ __launch_bounds__(256) void k_aggC8(const unsigned char* __restrict__ hs,
                                               const int* __restrict__ rp,
                                               const int* __restrict__ colx,
                                               const float* __restrict__ bias,
                                               _Float16* __restrict__ out, int N) {
    int wave = (blockIdx.x * 256 + threadIdx.x) >> 6;
    int lane = threadIdx.x & 63;
    if (wave >= N) return;
    int i = wave;
    int q = lane >> 4;
    int c8 = lane & 15;

    uint2 sw = *(const uint2*)(hs + (size_t)i * 128 + c8 * 8);
    int k0 = rp[i], k1 = rp[i + 1];

    float2_t a2[4] = {{0.f, 0.f}, {0.f, 0.f}, {0.f, 0.f}, {0.f, 0.f}};
    for (int k = k0 + q; k < k1; k += 4) {
        uint2 vv = *(const uint2*)(hs + (size_t)colx[k] * 128 + c8 * 8);
        acc8(vv, a2);
    }

    float a[8] = {a2[0].x, a2[0].y, a2[1].x, a2[1].y,
                  a2[2].x, a2[2].y, a2[3].x, a2[3].y};
    #pragma unroll
    for (int t = 0; t < 8; t++) {
        float x = a[t];
        x += __shfl_xor(x, 16);
        x += __shfl_xor(x, 32);
        a[t] = x;
    }

    if (q == 0) {
        float d = rsqrtf((float)(k1 - k0 + 1));
        float4 bA = ((const float4*)bias)[2 * c8];
        float4 bB = ((const float4*)bias)[2 * c8 + 1];
        float bb[8] = {bA.x, bA.y, bA.z, bA.w, bB.x, bB.y, bB.z, bB.w};
        float sf[8];
        f8x4(sw.x, sf);
        f8x4(sw.y, sf + 4);
        half8_t o;
        #pragma unroll
        for (int t = 0; t < 8; t++)
            o[t] = (_Float16)fmaf(a[t] + sf[t], d, bb[t]);
        ((half8_t*)out)[(size_t)i * 16 + c8] = o;
    }
}

// ---------------- BN stats (fp16 input) ----------------

__global__ __launch_bounds__(256) void k_stats(const _Float16* __restrict__ x, int N,
                                               float* __restrict__ sums) {
    int lane = threadIdx.x & 63;
    int wv = threadIdx.x >> 6;
    int gw = blockIdx.x * 4 + wv;
    int stride = gridDim.x * 4;
    const half2_t* b = (const half2_t*)x;
    float2 s = make_float2(0.f, 0.f), q = make_float2(0.f, 0.f);
    for (int i = gw; i < N; i += stride) {
        half2_t v = b[(size_t)i * 64 + lane];
        float vx = (float)v.x, vy = (float)v.y;
        s.x += vx; s.y += vy;
        q.x += vx * vx; q.y += vy * vy;
    }
    __shared__ float ls[4][128];
    __shared__ float lq[4][128];
    ls[wv][2 * lane] = s.x; ls[wv][2 * lane + 1] = s.y;
    lq[wv][2 * lane] = q.x; lq[wv][2 * lane + 1] = q.y;
    __syncthreads();
    int t = threadIdx.x;
    if (t < 128) {
        float ts = ls[0][t] + ls[1][t] + ls[2][t] + ls[3][t];
        float tq = lq[0][t] + lq[1][t] + lq[2][t] + lq[3][t];
        atomicAdd(&sums[t], ts);
        atomicAdd(&sums[128 + t], tq);
    }
}

// ---------------- Pooling: node-parallel, per-wave run flush (fp16 input) ----------------
// BN2 params computed per-block from sums.

__global__ __launch_bounds__(256) void k_pool2(const _Float16* __restrict__ x,
                                               const int* __restrict__ batch,
                                               const float* __restrict__ sums,
                                               const float* __restrict__ g2,
                                               const float* __restrict__ be2,
                                               float* __restrict__ psum, int N) {
    __shared__ alignas(8) float ss[128];
    __shared__ alignas(8) float hh[128];
    int t = threadIdx.x;
    if (t < 128) {
        float invN = 1.0f / (float)N;
        float mu = sums[t] * invN;
        float var = fmaxf(sums[128 + t] * invN - mu * mu, 0.f);
        float sc = g2[t] * rsqrtf(var + 1e-5f);
        ss[t] = sc;
        hh[t] = fmaf(-mu, sc, be2[t]);
    }
    __syncthreads();

    int nw = gridDim.x * 4;
    int w = blockIdx.x * 4 + (threadIdx.x >> 6);
    int lane = threadIdx.x & 63;
    int per = (N + nw - 1) / nw;
    int i0 = w * per, i1 = min(N, i0 + per);
    if (i0 >= i1) return;
    const half2_t* b = (const half2_t*)x;
    float2 s2 = ((const float2*)ss)[lane];
    float2 h2 = ((const float2*)hh)[lane];
    float2 acc = make_float2(0.f, 0.f);
    int g = batch[i0];
    for (int i = i0; i < i1; i++) {
        int gi = batch[i];
        if (gi != g) {   // wave-uniform branch
            atomicAdd(&psum[g * 128 + 2 * lane], acc.x);
            atomicAdd(&psum[g * 128 + 2 * lane + 1], acc.y);
            acc = make_float2(0.f, 0.f);
            g = gi;
        }
        half2_t v = b[(size_t)i * 64 + lane];
        acc.x += fmaxf(fmaf((float)v.x, s2.x, h2.x), 0.f);
        acc.y += fmaxf(fmaf((float)v.y, s2.y, h2.y), 0.f);
    }
    atomicAdd(&psum[g * 128 + 2 * lane], acc.x);
    atomicAdd(&psum[g * 128 + 2 * lane + 1], acc.y);
}

// ---------------- Head: out[g][o] = (psum[g]/cnt[g]) @ Wout[:,o] + bout[o] ----------------

__global__ __launch_bounds__(64) void k_final(const float* __restrict__ psum,
                                              const int* __restrict__ gptr,
                                              const float* __restrict__ Wout,
                                              const float* __restrict__ bout,
                                              float* __restrict__ out, int O) {
    int g = blockIdx.x, o = threadIdx.x;
    int cnt = gptr[g + 1] - gptr[g];
    float inv = 1.0f / fmaxf((float)cnt, 1.f);
    float acc = 0.f;
    for (int c = 0; c < 128; c++) acc = fmaf(psum[g * 128 + c], Wout[c * O + o], acc);
    out[g * O + o] = fmaf(acc, inv, bout[o]);
}

// ---------------- Host launch ----------------

extern "C" void kernel_launch(void* const* d_in, const int* in_sizes, int n_in,
                              void* d_out, int out_size, void* d_ws, size_t ws_size,
                              hipStream_t stream) {
    const float* x    = (const float*)d_in[0];
    const int*   edge = (const int*)d_in[1];
    const int*   batch= (const int*)d_in[2];
    const float* W0   = (const float*)d_in[4];
    const float* b0   = (const float*)d_in[5];
    const float* g0   = (const float*)d_in[6];
    const float* be0  = (const float*)d_in[7];
    const float* W1   = (const float*)d_in[8];
    const float* b1   = (const float*)d_in[9];
    const float* g1   = (const float*)d_in[10];
    const float* be1  = (const float*)d_in[11];
    const float* Wout = (const float*)d_in[12];
    const float* bout = (const float*)d_in[13];
    float* out = (float*)d_out;

    const int Hh  = in_sizes[5];              // 128
    const int Fin = in_sizes[4] / Hh;         // 128
    const int N   = in_sizes[0] / Fin;        // 100000
    const int E   = in_sizes[1] / 2;          // 1600000
    const int O   = in_sizes[13];             // 64
    const int G   = out_size / O;             // 128
    (void)Hh; (void)n_in;

    // bucket shift: smallest SH >= 8 with <= 512 buckets (pack needs SH <= 9, N < 2^23)
    int SH = 8;
    while (((N + (1 << SH) - 1) >> SH) > 512) SH++;
    const int NBK = (N + (1 << SH) - 1) >> SH;
    const int CH  = ((E + 255) / 256 > 8192) ? (E + 255) / 256 : 8192;  // chunk, keep WG<=256
    const int WG  = (E + CH - 1) / CH;

    char* p = (char*)d_ws;
    auto alloc = [&](size_t bytes) -> void* {
        void* r = (void*)p;
        p += (bytes + 255) & ~(size_t)255;
        return r;
    };
    unsigned char* A8 = (unsigned char*)alloc((size_t)(N + 1) * 128); // fp8 gather table + zero row
    _Float16* B   = (_Float16*)alloc((size_t)N * 128 * 2);            // fp16 layer output
    float* dinv   = (float*)alloc((size_t)N * 4);
    int*   rp     = (int*)alloc((size_t)(N + 1) * 4);
    int*   colx   = (int*)alloc((size_t)E * 4);
    unsigned* ebuf= (unsigned*)alloc((size_t)E * 4);
    int*   M      = (int*)alloc((size_t)NBK * WG * 4);
    int*   totals = (int*)alloc((size_t)NBK * 4);
    int*   base   = (int*)alloc((size_t)(NBK + 1) * 4);
    float* sums   = (float*)alloc(512 * 4);   // [sum1|sq1|sum2|sq2]
    int*   gptr   = (int*)alloc((size_t)(G + 1) * 4);
    float* psum   = (float*)alloc((size_t)G * 128 * 4);
    _Float16* Wt0 = (_Float16*)alloc(128 * 128 * 2);
    _Float16* Wt1 = (_Float16*)alloc(128 * 128 * 2);
    int*   slots  = (int*)alloc((size_t)N * 32 * 4);   // fixed-width gather slots
    bool useSlots = ((size_t)(p - (char*)d_ws) <= ws_size);
    if (!useSlots) slots = nullptr;

    const int* src = edge;
    const int* dst = edge + E;

    // radix-partition CSR build (LDS atomics); cntfill also does side jobs
    k_hist<<<WG, 256, NBK * 4, stream>>>(dst, E, SH, NBK, WG, CH, M);
    k_colscan<<<NBK, 256, 0, stream>>>(M, WG, totals);
    k_bucketscan<<<1, 512, 0, stream>>>(totals, NBK, E, base);
    k_scatter<<<WG, 256, NBK * 4, stream>>>(src, dst, E, SH, NBK, WG, CH, M, base, ebuf);
    k_cntfill<<<NBK, 256, 0, stream>>>(ebuf, base, SH, N, E, dinv, rp, colx, slots,
                                       W0, W1, Wt0, Wt1, batch, G, gptr, psum, sums, A8);

    // Layer 1 (MFMA GEMM fp32 in, fp8 out -> fp8 gather)
    k_gemmA<<<(N + 63) / 64, 256, 0, stream>>>(x, Wt0, dinv, A8, N);
    if (useSlots)
        k_aggS8<<<(N + 3) / 4, 256, 0, stream>>>(A8, slots, rp, colx, b0, B, N);
    else
        k_aggC8<<<(N + 3) / 4, 256, 0, stream>>>(A8, rp, colx, b0, B, N);
    k_stats<<<512, 256, 0, stream>>>(B, N, sums);

    // Layer 2 (fp16 in, BN1 params computed in-kernel, fp8 out -> fp8 gather)
    k_gemmB<<<(N + 63) / 64, 256, 0, stream>>>(B, Wt1, sums, g0, be0, dinv, A8, N);
    if (useSlots)
        k_aggS8<<<(N + 3) / 4, 256, 0, stream>>>(A8, slots, rp, colx, b1, B, N);
    else
        k_aggC8<<<(N + 3) / 4, 256, 0, stream>>>(A8, rp, colx, b1, B, N);
    k_stats<<<512, 256, 0, stream>>>(B, N, sums + 256);

    // Pool (BN2 computed in-kernel, BN+ReLU fused) + head (mean division fused)
    k_pool2<<<512, 256, 0, stream>>>(B, batch, sums + 256, g1, be1, psum, N);
    k_final<<<G, 64, 0, stream>>>(psum, gptr, Wout, bout, out, O);
}

// Round 17
// 339.412 us; speedup vs baseline: 1.2233x; 1.0459x over previous
//
#include <hip/hip_runtime.h>
#include <hip/hip_bf16.h>

typedef _Float16 half8_t __attribute__((ext_vector_type(8)));
typedef _Float16 half2_t __attribute__((ext_vector_type(2)));
typedef float float4_t __attribute__((ext_vector_type(4)));
typedef float float2_t __attribute__((ext_vector_type(2)));

#define WROW 136   // LDS Wt row pitch in halfs: 272B, 16B-aligned, bank-optimal

// ---------------- radix-partition CSR build ----------------
// bucket b = dst >> SH (SH=7 -> NBK=782: 3 cntfill blocks/CU vs 1.5 at SH=8).
// M[b*WG + w] = #edges of chunk w landing in bucket b; after k_colscan it is
// the per-chunk exclusive offset within bucket b. All hot counters are LDS
// (round-9 lesson: global scattered atomics cost ~10x the LDS-bucketed path).

__global__ __launch_bounds__(256) void k_hist(const int* __restrict__ dst, int E, int SH,
                                              int NBK, int WG, int CH, int* __restrict__ M) {
    extern __shared__ int lh[];
    for (int i = threadIdx.x; i < NBK; i += 256) lh[i] = 0;
    __syncthreads();
    int wg = blockIdx.x;
    int e0 = wg * CH, e1 = min(E, e0 + CH);
    for (int e = e0 + threadIdx.x; e < e1; e += 256)
        atomicAdd(&lh[dst[e] >> SH], 1);
    __syncthreads();
    for (int i = threadIdx.x; i < NBK; i += 256) M[i * WG + wg] = lh[i];
}

__global__ __launch_bounds__(256) void k_colscan(int* __restrict__ M, int WG,
                                                 int* __restrict__ totals) {
    __shared__ int s[256];
    int b = blockIdx.x, t = threadIdx.x;
    int v = (t < WG) ? M[b * WG + t] : 0;
    s[t] = v;
    __syncthreads();
    for (int off = 1; off < 256; off <<= 1) {
        int u = (t >= off) ? s[t - off] : 0;
        __syncthreads();
        s[t] += u;
        __syncthreads();
    }
    if (t < WG) M[b * WG + t] = s[t] - v;   // exclusive within bucket
    if (t == 255) totals[b] = s[255];
}

// 1024-thread scan: supports NBK up to 1024 (needed for SH=7 -> 782 buckets)
__global__ __launch_bounds__(1024) void k_bucketscan(const int* __restrict__ totals, int NBK,
                                                     int E, int* __restrict__ base) {
    __shared__ int s[1024];
    int t = threadIdx.x;
    int v = (t < NBK) ? totals[t] : 0;
    s[t] = v;
    __syncthreads();
    for (int off = 1; off < 1024; off <<= 1) {
        int u = (t >= off) ? s[t - off] : 0;
        __syncthreads();
        s[t] += u;
        __syncthreads();
    }
    if (t < NBK) base[t] = s[t] - v;
    if (t == 0) base[NBK] = E;
}

// pack: low 23 bits = src node, high 9 bits = dst - (b<<SH). Valid for N < 2^23, SH <= 9.
__global__ __launch_bounds__(256) void k_scatter(const int* __restrict__ src,
                                                 const int* __restrict__ dst, int E, int SH,
                                                 int NBK, int WG, int CH,
                                                 const int* __restrict__ M,
                                                 const int* __restrict__ base,
                                                 unsigned* __restrict__ ebuf) {
    extern __shared__ int cur[];
    int wg = blockIdx.x;
    for (int i = threadIdx.x; i < NBK; i += 256) cur[i] = base[i] + M[i * WG + wg];
    __syncthreads();
    int e0 = wg * CH, e1 = min(E, e0 + CH);
    for (int e = e0 + threadIdx.x; e < e1; e += 256) {
        int d = dst[e];
        int b = d >> SH;
        int pos = atomicAdd(&cur[b], 1);                 // LDS atomic, wg-private
        ebuf[pos] = (unsigned)src[e] | ((unsigned)(d - (b << SH)) << 23);
    }
}

// one wg per bucket (<=128 nodes at SH=7): LDS degree histogram -> pair-scan
// -> rp/dinv, then second ebuf pass writes the STRIDED slot table (offset
// off -> idx (off&3)*8 + off>>2, quarter q owns offsets q, q+4, ...). Slots
// NOT prefilled -- agg masks by off < deg. colx written ONLY for overflow
// offsets >= 32. Idle-capacity side jobs: blocks 0..63 Wt transpose; 64 gptr
// search; 65..96 psum zero; 97 sums zero + fp8 zero-row of A8.
__global__ __launch_bounds__(256) void k_cntfill(const unsigned* __restrict__ ebuf,
                                                 const int* __restrict__ base, int SH, int N,
                                                 int E, float* __restrict__ dinv,
                                                 int* __restrict__ rp, int* __restrict__ colx,
                                                 int* __restrict__ slots,
                                                 const float* __restrict__ W0,
                                                 const float* __restrict__ W1,
                                                 _Float16* __restrict__ Wt0,
                                                 _Float16* __restrict__ Wt1,
                                                 const int* __restrict__ batch, int G,
                                                 int* __restrict__ gptr,
                                                 float* __restrict__ psum,
                                                 float* __restrict__ sums,
                                                 unsigned char* __restrict__ A8) {
    __shared__ int h[128];
    __shared__ int cur[128];
    __shared__ int rs[128];
    __shared__ int lim[128];
    __shared__ int s[256];
    int b = blockIdx.x, t = threadIdx.x;

    // side jobs
    if (b < 64) {
        int idx = b * 256 + t;            // 16384 elements over 64 blocks
        int n = idx >> 7, k = idx & 127;
        Wt0[n * 128 + k] = (_Float16)W0[k * 128 + n];
        Wt1[n * 128 + k] = (_Float16)W1[k * 128 + n];
    } else if (b == 64) {
        if (t <= G) {
            int g = t;
            int lo = 0, hi = N;
            while (lo < hi) {
                int mid = (lo + hi) >> 1;
                if (batch[mid] < g) lo = mid + 1; else hi = mid;
            }
            gptr[g] = lo;
        }
    } else if (b < 97) {
        int i0 = (b - 65) * 512 + t;      // G*128 = 16384 floats over 32 blocks
        psum[i0] = 0.f;
        psum[i0 + 256] = 0.f;
    } else if (b == 97) {
        if (t < 256) { sums[t] = 0.f; sums[t + 256] = 0.f; }
        // fp8 zero row at index N (mask target; e4m3 0.0 == 0x00)
        if (t < 32) ((unsigned*)A8)[(size_t)N * 32 + t] = 0u;
    }

    // main cntfill work (bucket width <= 128)
    int n0 = b << SH;
    int nb = min(N - n0, 1 << SH);
    if (t < 128 && t < nb) h[t] = 0;
    __syncthreads();
    int e0 = base[b], e1 = base[b + 1];
    for (int e = e0 + t; e < e1; e += 256)
        atomicAdd(&h[ebuf[e] >> 23], 1);
    __syncthreads();
    int i0 = 2 * t, i1 = 2 * t + 1;
    int a0 = (i0 < nb) ? h[i0] : 0;
    int a1 = (i1 < nb) ? h[i1] : 0;
    int ps = a0 + a1;
    s[t] = ps;
    __syncthreads();
    for (int off = 1; off < 256; off <<= 1) {
        int u = (t >= off) ? s[t - off] : 0;
        __syncthreads();
        s[t] += u;
        __syncthreads();
    }
    int excl = s[t] - ps;
    if (i0 < nb) {
        int r0 = e0 + excl;
        cur[i0] = r0;
        rs[i0] = r0;
        lim[i0] = min(a0, 32);
        rp[n0 + i0] = r0;
        dinv[n0 + i0] = rsqrtf((float)(a0 + 1));
    }
    if (i1 < nb) {
        int r1 = e0 + excl + a0;
        cur[i1] = r1;
        rs[i1] = r1;
        lim[i1] = min(a1, 32);
        rp[n0 + i1] = r1;
        dinv[n0 + i1] = rsqrtf((float)(a1 + 1));
    }
    if (b == (int)gridDim.x - 1 && t == 0) rp[N] = E;
    __syncthreads();
    for (int e = e0 + t; e < e1; e += 256) {
        unsigned v = ebuf[e];
        int local = (int)(v >> 23);
        int srcn = (int)(v & 0x7FFFFFu);
        int pos = atomicAdd(&cur[local], 1);             // LDS atomic, wg-private
        int off = pos - rs[local];
        if (slots && off < lim[local]) {
            int idx = ((off & 3) << 3) + (off >> 2);     // strided layout
            slots[(size_t)(n0 + local) * 32 + idx] = srcn;
        } else {
            colx[pos] = srcn;                            // overflow (or no-slots fallback)
        }
    }
}

// ---------------- MFMA GEMM layer 1: out = fp8((X@W)*dinv) ----------------
// Wt staged in LDS (round-16: fixed the VGPR=20 serialized-load stall;
// gemms dropped below top-5). Batch-issue all X loads, inner loop is
// ds_read+MFMA. 64-row blocks, 4 waves x 8 tiles, WROW=136 pad.

__global__ __launch_bounds__(256) void k_gemmA(const float* __restrict__ X,
                                               const _Float16* __restrict__ Wt,
                                               const float* __restrict__ dinv,
                                               unsigned char* __restrict__ out, int N) {
    __shared__ _Float16 w[128 * WROW];
    int t = threadIdx.x;
    #pragma unroll
    for (int i = 0; i < 8; i++) {
        int idx = t + i * 256;            // 2048 chunks of 8 halfs
        int n = idx >> 4, k = (idx & 15) * 8;
        *(half8_t*)&w[n * WROW + k] = *(const half8_t*)(Wt + n * 128 + k);
    }
    __syncthreads();

    int wv = t >> 6, lane = t & 63;
    int m = lane & 15, quad = lane >> 4;
    int rowbase = blockIdx.x * 64 + wv * 16;
    int arow = rowbase + m;
    int arowc = (arow < N) ? arow : (N - 1);
    const float* xr = X + (size_t)arowc * 128;

    // batch-issue all X loads (one memory epoch per wave)
    float4_t xa[4], xb[4];
    #pragma unroll
    for (int kc = 0; kc < 4; kc++) {
        xa[kc] = *(const float4_t*)(xr + kc * 32 + quad * 8);
        xb[kc] = *(const float4_t*)(xr + kc * 32 + quad * 8 + 4);
    }
    half8_t a[4];
    #pragma unroll
    for (int kc = 0; kc < 4; kc++) {
        #pragma unroll
        for (int j = 0; j < 4; j++) a[kc][j] = (_Float16)xa[kc][j];
        #pragma unroll
        for (int j = 0; j < 4; j++) a[kc][4 + j] = (_Float16)xb[kc][j];
    }

    float4_t acc[8];
    #pragma unroll
    for (int i = 0; i < 8; i++) acc[i] = (float4_t){0.f, 0.f, 0.f, 0.f};

    #pragma unroll
    for (int nt = 0; nt < 8; nt++) {
        const _Float16* wr = &w[(nt * 16 + m) * WROW + quad * 8];
        #pragma unroll
        for (int kc = 0; kc < 4; kc++) {
            half8_t b = *(const half8_t*)(wr + kc * 32);
            acc[nt] = __builtin_amdgcn_mfma_f32_16x16x32_f16(a[kc], b, acc[nt], 0, 0, 0);
        }
    }

    #pragma unroll
    for (int r = 0; r < 4; r++) {
        int row = rowbase + quad * 4 + r;
        if (row < N) {
            float dv = dinv[row];
            unsigned char* o = out + (size_t)row * 128 + m;
            #pragma unroll
            for (int nt = 0; nt < 8; nt++) {
                float v = acc[nt][r] * dv;
                int pk = __builtin_amdgcn_cvt_pk_fp8_f32(v, v, 0, false);
                o[nt * 16] = (unsigned char)(pk & 0xFF);
            }
        }
    }
}

// fp16-input variant, layer 2: Wt in LDS, BN params computed per-block from
// sums, BN+ReLU fused into A-frag conversion, fp8 output.
__global__ __launch_bounds__(256) void k_gemmB(const _Float16* __restrict__ X,
                                               const _Float16* __restrict__ Wt,
                                               const float* __restrict__ sums,
                                               const float* __restrict__ g,
                                               const float* __restrict__ be,
                                               const float* __restrict__ dinv,
                                               unsigned char* __restrict__ out, int N) {
    __shared__ _Float16 w[128 * WROW];
    __shared__ alignas(16) float ss[128];
    __shared__ alignas(16) float hh[128];
    int t = threadIdx.x;
    if (t < 128) {
        float invN = 1.0f / (float)N;
        float mu = sums[t] * invN;
        float var = fmaxf(sums[128 + t] * invN - mu * mu, 0.f);
        float sc = g[t] * rsqrtf(var + 1e-5f);
        ss[t] = sc;
        hh[t] = fmaf(-mu, sc, be[t]);
    }
    #pragma unroll
    for (int i = 0; i < 8; i++) {
        int idx = t + i * 256;
        int n = idx >> 4, k = (idx & 15) * 8;
        *(half8_t*)&w[n * WROW + k] = *(const half8_t*)(Wt + n * 128 + k);
    }
    __syncthreads();

    int wv = t >> 6, lane = t & 63;
    int m = lane & 15, quad = lane >> 4;
    int rowbase = blockIdx.x * 64 + wv * 16;
    int arow = rowbase + m;
    int arowc = (arow < N) ? arow : (N - 1);
    const _Float16* xr = X + (size_t)arowc * 128;

    // batch-issue all X loads
    half8_t x8[4];
    #pragma unroll
    for (int kc = 0; kc < 4; kc++)
        x8[kc] = *(const half8_t*)(xr + kc * 32 + quad * 8);

    half8_t a[4];
    #pragma unroll
    for (int kc = 0; kc < 4; kc++) {
        int k0 = kc * 32 + quad * 8;
        float4_t sa = *(const float4_t*)(ss + k0);
        float4_t sb = *(const float4_t*)(ss + k0 + 4);
        float4_t ha = *(const float4_t*)(hh + k0);
        float4_t hb = *(const float4_t*)(hh + k0 + 4);
        #pragma unroll
        for (int j = 0; j < 4; j++)
            a[kc][j] = (_Float16)fmaxf(fmaf((float)x8[kc][j], sa[j], ha[j]), 0.f);
        #pragma unroll
        for (int j = 0; j < 4; j++)
            a[kc][4 + j] = (_Float16)fmaxf(fmaf((float)x8[kc][4 + j], sb[j], hb[j]), 0.f);
    }

    float4_t acc[8];
    #pragma unroll
    for (int i = 0; i < 8; i++) acc[i] = (float4_t){0.f, 0.f, 0.f, 0.f};

    #pragma unroll
    for (int nt = 0; nt < 8; nt++) {
        const _Float16* wr = &w[(nt * 16 + m) * WROW + quad * 8];
        #pragma unroll
        for (int kc = 0; kc < 4; kc++) {
            half8_t b = *(const half8_t*)(wr + kc * 32);
            acc[nt] = __builtin_amdgcn_mfma_f32_16x16x32_f16(a[kc], b, acc[nt], 0, 0, 0);
        }
    }

    #pragma unroll
    for (int r = 0; r < 4; r++) {
        int row = rowbase + quad * 4 + r;
        if (row < N) {
            float dv = dinv[row];
            unsigned char* o = out + (size_t)row * 128 + m;
            #pragma unroll
            for (int nt = 0; nt < 8; nt++) {
                float v = acc[nt][r] * dv;
                int pk = __builtin_amdgcn_cvt_pk_fp8_f32(v, v, 0, false);
                o[nt * 16] = (unsigned char)(pk & 0xFF);
            }
        }
    }
}

// ---------------- Aggregation: fp8 table + strided slots, degree-tiered ----------------
// out[i] = dinv[i]*(hs[i] + sum_j hs[j]) + b, fp16 out. One wave per node.
// Quarter q owns edge offsets q, q+4, ...; validity mask off < deg (slots
// unprefilled, garbage never dereferenced). deg>32 remainder reads
// colx[k0+32..k1). Decode: cvt_pk_f32_fp8 into float2 accumulators.

__device__ __forceinline__ void acc8(uint2 v, float2_t* a2) {
    a2[0] += __builtin_amdgcn_cvt_pk_f32_fp8((int)v.x, false);
    a2[1] += __builtin_amdgcn_cvt_pk_f32_fp8((int)v.x, true);
    a2[2] += __builtin_amdgcn_cvt_pk_f32_fp8((int)v.y, false);
    a2[3] += __builtin_amdgcn_cvt_pk_f32_fp8((int)v.y, true);
}

__device__ __forceinline__ void f8x4(unsigned w, float* o) {
    o[0] = __builtin_amdgcn_cvt_f32_fp8((int)w, 0);
    o[1] = __builtin_amdgcn_cvt_f32_fp8((int)w, 1);
    o[2] = __builtin_amdgcn_cvt_f32_fp8((int)w, 2);
    o[3] = __builtin_amdgcn_cvt_f32_fp8((int)w, 3);
}

__global__ __launch_bounds__(256) void k_aggS8(const unsigned char* __restrict__ hs,
                                               const int* __restrict__ slots,
                                               const int* __restrict__ rp,
                                               const int* __restrict__ colx,
                                               const float* __restrict__ bias,
                                               _Float16* __restrict__ out, int N) {
    int wave = (blockIdx.x * 256 + threadIdx.x) >> 6;
    int lane = threadIdx.x & 63;
    if (wave >= N) return;
    int i = wave;
    int q = lane >> 4;            // quarter 0..3
    int c8 = lane & 15;           // channels 8*c8 .. 8*c8+7

    const int4* sl4 = (const int4*)(slots + (size_t)i * 32 + 8 * q);
    int4 sa = sl4[0];
    int k0 = rp[i], k1 = rp[i + 1];
    uint2 sw = *(const uint2*)(hs + (size_t)i * 128 + c8 * 8);   // self row
    int deg = k1 - k0;

    float2_t a2[4] = {{0.f, 0.f}, {0.f, 0.f}, {0.f, 0.f}, {0.f, 0.f}};

    // tier 1: edge offsets q, q+4, q+8, q+12 (covers deg<=16)
    {
        int jraw[4] = {sa.x, sa.y, sa.z, sa.w};
        int j[4];
        #pragma unroll
        for (int s = 0; s < 4; s++)
            j[s] = (q + 4 * s < deg) ? jraw[s] : N;   // mask unwritten slots
        uint2 v[4];
        #pragma unroll
        for (int s = 0; s < 4; s++)
            v[s] = *(const uint2*)(hs + (size_t)j[s] * 128 + c8 * 8);
        #pragma unroll
        for (int s = 0; s < 4; s++) acc8(v[s], a2);
    }
    if (deg > 16) {               // tier 2: offsets 16..31 (wave-uniform)
        int4 sb = sl4[1];
        int jraw[4] = {sb.x, sb.y, sb.z, sb.w};
        int j[4];
        #pragma unroll
        for (int s = 0; s < 4; s++)
            j[s] = (16 + q + 4 * s < deg) ? jraw[s] : N;
        uint2 v[4];
        #pragma unroll
        for (int s = 0; s < 4; s++)
            v[s] = *(const uint2*)(hs + (size_t)j[s] * 128 + c8 * 8);
        #pragma unroll
        for (int s = 0; s < 4; s++) acc8(v[s], a2);
        if (deg > 32) {           // rare remainder from colx (P ~ 1e-4)
            for (int k = k0 + 32 + q; k < k1; k += 4) {
                uint2 vv = *(const uint2*)(hs + (size_t)colx[k] * 128 + c8 * 8);
                acc8(vv, a2);
            }
        }
    }

    // cross-quarter reduce over lanes {l, l+16, l+32, l+48}
    float a[8] = {a2[0].x, a2[0].y, a2[1].x, a2[1].y,
                  a2[2].x, a2[2].y, a2[3].x, a2[3].y};
    #pragma unroll
    for (int t = 0; t < 8; t++) {
        float x = a[t];
        x += __shfl_xor(x, 16);
        x += __shfl_xor(x, 32);
        a[t] = x;
    }

    if (q == 0) {
        float d = rsqrtf((float)(deg + 1));
        float4 bA = ((const float4*)bias)[2 * c8];
        float4 bB = ((const float4*)bias)[2 * c8 + 1];
        float bb[8] = {bA.x, bA.y, bA.z, bA.w, bB.x, bB.y, bB.z, bB.w};
        float sf[8];
        f8x4(sw.x, sf);
        f8x4(sw.y, sf + 4);
        half8_t o;
        #pragma unroll
        for (int t = 0; t < 8; t++)
            o[t] = (_Float16)fmaf(a[t] + sf[t], d, bb[t]);
        ((half8_t*)out)[(size_t)i * 16 + c8] = o;
    }
}

// CSR fallback (fp8) if workspace can't hold the slot table (colx holds all).
__global__ __launch_bounds__(256) void k_aggC8(const unsigned char* __restrict__ hs,
                                               const int* __restrict__ rp,
                                               const int* __restrict__ colx,
                                               const float* __restrict__ bias,
                                               _Float16* __restrict__ out, int N) {
    int wave = (blockIdx.x * 256 + threadIdx.x) >> 6;
    int lane = threadIdx.x & 63;
    if (wave >= N) return;
    int i = wave;
    int q = lane >> 4;
    int c8 = lane & 15;

    uint2 sw = *(const uint2*)(hs + (size_t)i * 128 + c8 * 8);
    int k0 = rp[i], k1 = rp[i + 1];

    float2_t a2[4] = {{0.f, 0.f}, {0.f, 0.f}, {0.f, 0.f}, {0.f, 0.f}};
    for (int k = k0 + q; k < k1; k += 4) {
        uint2 vv = *(const uint2*)(hs + (size_t)colx[k] * 128 + c8 * 8);
        acc8(vv, a2);
    }

    float a[8] = {a2[0].x, a2[0].y, a2[1].x, a2[1].y,
                  a2[2].x, a2[2].y, a2[3].x, a2[3].y};
    #pragma unroll
    for (int t = 0; t < 8; t++) {
        float x = a[t];
        x += __shfl_xor(x, 16);
        x += __shfl_xor(x, 32);
        a[t] = x;
    }

    if (q == 0) {
        float d = rsqrtf((float)(k1 - k0 + 1));
        float4 bA = ((const float4*)bias)[2 * c8];
        float4 bB = ((const float4*)bias)[2 * c8 + 1];
        float bb[8] = {bA.x, bA.y, bA.z, bA.w, bB.x, bB.y, bB.z, bB.w};
        float sf[8];
        f8x4(sw.x, sf);
        f8x4(sw.y, sf + 4);
        half8_t o;
        #pragma unroll
        for (int t = 0; t < 8; t++)
            o[t] = (_Float16)fmaf(a[t] + sf[t], d, bb[t]);
        ((half8_t*)out)[(size_t)i * 16 + c8] = o;
    }
}

// ---------------- BN stats (fp16 input, 16B/lane vectorized) ----------------
// 16 lanes cover a 256B row via half8; 4 rows per wave per iteration; subs
// (lane>>4) combined via shfl_xor(16,32). G13: scalar-ish 4B/lane was ~2x.

__global__ __launch_bounds__(256) void k_stats(const _Float16* __restrict__ x, int N,
                                               float* __restrict__ sums) {
    int t = threadIdx.x;
    int lane = t & 63, wv = t >> 6;
    int sub = lane >> 4, c8 = lane & 15;
    int gw = blockIdx.x * 4 + wv;          // wave id
    int rstride = gridDim.x * 4 * 4;       // rows per sweep
    float s[8] = {0.f, 0.f, 0.f, 0.f, 0.f, 0.f, 0.f, 0.f};
    float q[8] = {0.f, 0.f, 0.f, 0.f, 0.f, 0.f, 0.f, 0.f};
    for (int row = gw * 4 + sub; row < N; row += rstride) {
        half8_t v = *(const half8_t*)(x + (size_t)row * 128 + c8 * 8);
        #pragma unroll
        for (int j = 0; j < 8; j++) {
            float f = (float)v[j];
            s[j] += f;
            q[j] += f * f;
        }
    }
    #pragma unroll
    for (int j = 0; j < 8; j++) {
        s[j] += __shfl_xor(s[j], 16); s[j] += __shfl_xor(s[j], 32);
        q[j] += __shfl_xor(q[j], 16); q[j] += __shfl_xor(q[j], 32);
    }
    __shared__ float ls[4][128];
    __shared__ float lq[4][128];
    if (sub == 0) {
        #pragma unroll
        for (int j = 0; j < 8; j++) {
            ls[wv][c8 * 8 + j] = s[j];
            lq[wv][c8 * 8 + j] = q[j];
        }
    }
    __syncthreads();
    if (t < 128) {
        float ts = ls[0][t] + ls[1][t] + ls[2][t] + ls[3][t];
        float tq = lq[0][t] + lq[1][t] + lq[2][t] + lq[3][t];
        atomicAdd(&sums[t], ts);
        atomicAdd(&sums[128 + t], tq);
    }
}

// ---------------- Pooling: node-parallel, per-wave run flush (fp16 input) ----------------
// BN2 params computed per-block from sums.

__global__ __launch_bounds__(256) void k_pool2(const _Float16* __restrict__ x,
                                               const int* __restrict__ batch,
                                               const float* __restrict__ sums,
                                               const float* __restrict__ g2,
                                               const float* __restrict__ be2,
                                               float* __restrict__ psum, int N) {
    __shared__ alignas(8) float ss[128];
    __shared__ alignas(8) float hh[128];
    int t = threadIdx.x;
    if (t < 128) {
        float invN = 1.0f / (float)N;
        float mu = sums[t] * invN;
        float var = fmaxf(sums[128 + t] * invN - mu * mu, 0.f);
        float sc = g2[t] * rsqrtf(var + 1e-5f);
        ss[t] = sc;
        hh[t] = fmaf(-mu, sc, be2[t]);
    }
    __syncthreads();

    int nw = gridDim.x * 4;
    int w = blockIdx.x * 4 + (threadIdx.x >> 6);
    int lane = threadIdx.x & 63;
    int per = (N + nw - 1) / nw;
    int i0 = w * per, i1 = min(N, i0 + per);
    if (i0 >= i1) return;
    const half2_t* b = (const half2_t*)x;
    float2 s2 = ((const float2*)ss)[lane];
    float2 h2 = ((const float2*)hh)[lane];
    float2 acc = make_float2(0.f, 0.f);
    int g = batch[i0];
    for (int i = i0; i < i1; i++) {
        int gi = batch[i];
        if (gi != g) {   // wave-uniform branch
            atomicAdd(&psum[g * 128 + 2 * lane], acc.x);
            atomicAdd(&psum[g * 128 + 2 * lane + 1], acc.y);
            acc = make_float2(0.f, 0.f);
            g = gi;
        }
        half2_t v = b[(size_t)i * 64 + lane];
        acc.x += fmaxf(fmaf((float)v.x, s2.x, h2.x), 0.f);
        acc.y += fmaxf(fmaf((float)v.y, s2.y, h2.y), 0.f);
    }
    atomicAdd(&psum[g * 128 + 2 * lane], acc.x);
    atomicAdd(&psum[g * 128 + 2 * lane + 1], acc.y);
}

// ---------------- Head: out[g][o] = (psum[g]/cnt[g]) @ Wout[:,o] + bout[o] ----------------

__global__ __launch_bounds__(64) void k_final(const float* __restrict__ psum,
                                              const int* __restrict__ gptr,
                                              const float* __restrict__ Wout,
                                              const float* __restrict__ bout,
                                              float* __restrict__ out, int O) {
    int g = blockIdx.x, o = threadIdx.x;
    int cnt = gptr[g + 1] - gptr[g];
    float inv = 1.0f / fmaxf((float)cnt, 1.f);
    float acc = 0.f;
    for (int c = 0; c < 128; c++) acc = fmaf(psum[g * 128 + c], Wout[c * O + o], acc);
    out[g * O + o] = fmaf(acc, inv, bout[o]);
}

// ---------------- Host launch ----------------

extern "C" void kernel_launch(void* const* d_in, const int* in_sizes, int n_in,
                              void* d_out, int out_size, void* d_ws, size_t ws_size,
                              hipStream_t stream) {
    const float* x    = (const float*)d_in[0];
    const int*   edge = (const int*)d_in[1];
    const int*   batch= (const int*)d_in[2];
    const float* W0   = (const float*)d_in[4];
    const float* b0   = (const float*)d_in[5];
    const float* g0   = (const float*)d_in[6];
    const float* be0  = (const float*)d_in[7];
    const float* W1   = (const float*)d_in[8];
    const float* b1   = (const float*)d_in[9];
    const float* g1   = (const float*)d_in[10];
    const float* be1  = (const float*)d_in[11];
    const float* Wout = (const float*)d_in[12];
    const float* bout = (const float*)d_in[13];
    float* out = (float*)d_out;

    const int Hh  = in_sizes[5];              // 128
    const int Fin = in_sizes[4] / Hh;         // 128
    const int N   = in_sizes[0] / Fin;        // 100000
    const int E   = in_sizes[1] / 2;          // 1600000
    const int O   = in_sizes[13];             // 64
    const int G   = out_size / O;             // 128
    (void)Hh; (void)n_in;

    // bucket shift: smallest SH >= 7 with <= 1024 buckets (pack needs SH <= 9)
    int SH = 7;
    while (((N + (1 << SH) - 1) >> SH) > 1024) SH++;
    const int NBK = (N + (1 << SH) - 1) >> SH;
    const int CH  = ((E + 255) / 256 > 8192) ? (E + 255) / 256 : 8192;  // chunk, keep WG<=256
    const int WG  = (E + CH - 1) / CH;

    char* p = (char*)d_ws;
    auto alloc = [&](size_t bytes) -> void* {
        void* r = (void*)p;
        p += (bytes + 255) & ~(size_t)255;
        return r;
    };
    unsigned char* A8 = (unsigned char*)alloc((size_t)(N + 1) * 128); // fp8 gather table + zero row
    _Float16* B   = (_Float16*)alloc((size_t)N * 128 * 2);            // fp16 layer output
    float* dinv   = (float*)alloc((size_t)N * 4);
    int*   rp     = (int*)alloc((size_t)(N + 1) * 4);
    int*   colx   = (int*)alloc((size_t)E * 4);
    unsigned* ebuf= (unsigned*)alloc((size_t)E * 4);
    int*   M      = (int*)alloc((size_t)NBK * WG * 4);
    int*   totals = (int*)alloc((size_t)NBK * 4);
    int*   base   = (int*)alloc((size_t)(NBK + 1) * 4);
    float* sums   = (float*)alloc(512 * 4);   // [sum1|sq1|sum2|sq2]
    int*   gptr   = (int*)alloc((size_t)(G + 1) * 4);
    float* psum   = (float*)alloc((size_t)G * 128 * 4);
    _Float16* Wt0 = (_Float16*)alloc(128 * 128 * 2);
    _Float16* Wt1 = (_Float16*)alloc(128 * 128 * 2);
    int*   slots  = (int*)alloc((size_t)N * 32 * 4);   // fixed-width gather slots
    bool useSlots = ((size_t)(p - (char*)d_ws) <= ws_size);
    if (!useSlots) slots = nullptr;

    const int* src = edge;
    const int* dst = edge + E;

    // radix-partition CSR build (LDS atomics); cntfill also does side jobs
    k_hist<<<WG, 256, NBK * 4, stream>>>(dst, E, SH, NBK, WG, CH, M);
    k_colscan<<<NBK, 256, 0, stream>>>(M, WG, totals);
    k_bucketscan<<<1, 1024, 0, stream>>>(totals, NBK, E, base);
    k_scatter<<<WG, 256, NBK * 4, stream>>>(src, dst, E, SH, NBK, WG, CH, M, base, ebuf);
    k_cntfill<<<NBK, 256, 0, stream>>>(ebuf, base, SH, N, E, dinv, rp, colx, slots,
                                       W0, W1, Wt0, Wt1, batch, G, gptr, psum, sums, A8);

    // Layer 1 (MFMA GEMM fp32 in, fp8 out -> fp8 gather)
    k_gemmA<<<(N + 63) / 64, 256, 0, stream>>>(x, Wt0, dinv, A8, N);
    if (useSlots)
        k_aggS8<<<(N + 3) / 4, 256, 0, stream>>>(A8, slots, rp, colx, b0, B, N);
    else
        k_aggC8<<<(N + 3) / 4, 256, 0, stream>>>(A8, rp, colx, b0, B, N);
    k_stats<<<512, 256, 0, stream>>>(B, N, sums);

    // Layer 2 (fp16 in, BN1 params computed in-kernel, fp8 out -> fp8 gather)
    k_gemmB<<<(N + 63) / 64, 256, 0, stream>>>(B, Wt1, sums, g0, be0, dinv, A8, N);
    if (useSlots)
        k_aggS8<<<(N + 3) / 4, 256, 0, stream>>>(A8, slots, rp, colx, b1, B, N);
    else
        k_aggC8<<<(N + 3) / 4, 256, 0, stream>>>(A8, rp, colx, b1, B, N);
    k_stats<<<512, 256, 0, stream>>>(B, N, sums + 256);

    // Pool (BN2 computed in-kernel, BN+ReLU fused) + head (mean division fused)
    k_pool2<<<512, 256, 0, stream>>>(B, batch, sums + 256, g1, be1, psum, N);
    k_final<<<G, 64, 0, stream>>>(psum, gptr, Wout, bout, out, O);
}